// Round 6
// baseline (156.594 us; speedup 1.0000x reference)
//
#include <hip/hip_runtime.h>
#include <math.h>

#define NTOT 4096
#define BSZH 2048
#define DIMK 256
#define GY   32            // 4096/128 tiles per dimension
#define BK   64

typedef __bf16 bf16x8 __attribute__((ext_vector_type(8)));
typedef __bf16 bf16x4 __attribute__((ext_vector_type(4)));
typedef float  f32x4  __attribute__((ext_vector_type(4)));

// fp32 -> bf16 convert + row squared norms + zero the output scalar.
__global__ __launch_bounds__(256) void k_prep(const float* __restrict__ f,
                                              __bf16* __restrict__ fb,
                                              float* __restrict__ sq,
                                              float* __restrict__ out) {
    if (blockIdx.x == 0 && threadIdx.x == 0) out[0] = 0.0f;
    int row  = blockIdx.x * 4 + (threadIdx.x >> 6);
    int lane = threadIdx.x & 63;
    float4 v = *(const float4*)(f + row * DIMK + lane * 4);
    bf16x4 pk;
    pk[0] = (__bf16)v.x; pk[1] = (__bf16)v.y; pk[2] = (__bf16)v.z; pk[3] = (__bf16)v.w;
    *(bf16x4*)(fb + row * DIMK + lane * 4) = pk;
    float s = v.x*v.x + v.y*v.y + v.z*v.z + v.w*v.w;
    #pragma unroll
    for (int off = 32; off > 0; off >>= 1) s += __shfl_xor(s, off, 64);
    if (lane == 0) sq[row] = s;
}

// 128x128 tile (bx <= by only; sim is symmetric). LDS-staged bf16 MFMA gram
// + fused sim epilogue. Row partials keyed by (row, by); for bx<by also
// column partials (transposed tile) keyed by (col, bx). Shift-free softmax:
// row max == diag == 7.142857 (dsim<=0, ang<=1), folded into k_final.
__global__ __launch_bounds__(256) void k_main(const __bf16* __restrict__ fb,
                                              const int* __restrict__ labels,
                                              const float* __restrict__ sq,
                                              float4* __restrict__ part) {
    const int bx = blockIdx.x, by = blockIdx.y;
    if (bx > by) return;

    __shared__ __align__(16) __bf16 As[128 * BK];   // [row][k], 128B rows, blocks XOR-swizzled
    __shared__ __align__(16) __bf16 Bs[128 * BK];
    __shared__ float redR[2][2][64][3];             // [wr][wc][row_local][T,P,N]
    __shared__ float redC[2][2][64][3];             // [wc][wr][col_local][T,P,N]

    const int tid = threadIdx.x;
    const int wid = tid >> 6, lane = tid & 63;
    const int l15 = lane & 15, lg = lane >> 4;
    const int wr  = wid >> 1,  wc = wid & 1;
    const int trow = bx * 128, tcol = by * 128;

    // staging: 8 x 16B per thread (q<4 -> A-tile, q>=4 -> B-tile).
    // LDS dest is LINEAR block b of row r; global source is block b^(r&7)
    // (pre-swizzle), so phys block P holds logical block P^(r&7).
    const __bf16* sp[8];
    int soff[8];
    #pragma unroll
    for (int q = 0; q < 8; ++q) {
        int idx = ((q & 3) << 8) | tid;        // 0..1023 16B-blocks
        int r = idx >> 3, b = idx & 7;
        int gb = b ^ (r & 7);
        sp[q]   = fb + (size_t)((q < 4 ? trow : tcol) + r) * DIMK + (gb << 3);
        soff[q] = r * 128 + b * 16;
    }

    uint4 gv[8];
    #pragma unroll
    for (int q = 0; q < 8; ++q) gv[q] = *(const uint4*)sp[q];

    f32x4 acc[4][4];
    #pragma unroll
    for (int i = 0; i < 4; ++i)
        #pragma unroll
        for (int j = 0; j < 4; ++j) acc[i][j] = (f32x4){0.f, 0.f, 0.f, 0.f};

    const int sw = l15 & 7;    // (frag_row & 7): rows are l15 + multiples of 16

    for (int ks = 0; ks < 4; ++ks) {
        __syncthreads();                        // LDS free (prev compute done)
        #pragma unroll
        for (int q = 0; q < 8; ++q)
            *(uint4*)(((q < 4) ? (char*)As : (char*)Bs) + soff[q]) = gv[q];
        __syncthreads();                        // tiles ready
        if (ks < 3) {                           // prefetch next K-step under compute
            #pragma unroll
            for (int q = 0; q < 8; ++q) gv[q] = *(const uint4*)(sp[q] + (ks + 1) * BK);
        }
        #pragma unroll
        for (int sub = 0; sub < 2; ++sub) {
            const int P = (((lg + (sub << 2)) ^ sw) << 4);   // swizzled block byte offset
            bf16x8 av[4], bv[4];
            #pragma unroll
            for (int i = 0; i < 4; ++i) {
                av[i] = *(const bf16x8*)((const char*)As + (wr * 64 + i * 16 + l15) * 128 + P);
                bv[i] = *(const bf16x8*)((const char*)Bs + (wc * 64 + i * 16 + l15) * 128 + P);
            }
            #pragma unroll
            for (int i = 0; i < 4; ++i)
                #pragma unroll
                for (int j = 0; j < 4; ++j)
                    acc[i][j] = __builtin_amdgcn_mfma_f32_16x16x32_bf16(av[i], bv[j], acc[i][j], 0, 0, 0);
        }
    }

    // ---- epilogue ----
    float cb2[4], cb2p[4], cb01[4], cinv[4]; int clab[4], ccol[4];
    #pragma unroll
    for (int j = 0; j < 4; ++j) {
        int col = tcol + wc * 64 + j * 16 + l15;
        float b2 = sq[col];
        ccol[j] = col; cb2[j] = b2;
        cb2p[j] = fmaf(0.01f, b2, 1.0f);
        cb01[j] = 0.01f * b2;
        cinv[j] = __frsqrt_rn(fmaxf(b2, 1e-24f));
        clab[j] = labels[col & (BSZH - 1)];
    }

    float cT[4], cP[4], cN[4];
    #pragma unroll
    for (int j = 0; j < 4; ++j) { cT[j] = 0.f; cP[j] = 0.f; cN[j] = 0.f; }

    #pragma unroll
    for (int i = 0; i < 4; ++i) {
        float rT[4], rP[4], rN[4];
        float ra2[4], rinv[4], Bv[4], B2v[4]; int rlab[4], rrow[4];
        #pragma unroll
        for (int t = 0; t < 4; ++t) {
            rT[t] = 0.f; rP[t] = 0.f; rN[t] = 0.f;
            int row = trow + wr * 64 + i * 16 + lg * 4 + t;
            float a2 = sq[row];
            rrow[t] = row; ra2[t] = a2;
            rinv[t] = __frsqrt_rn(fmaxf(a2, 1e-24f));
            rlab[t] = labels[row & (BSZH - 1)];
            float B = fmaf(-0.01f, a2, 1.0f);
            Bv[t] = B; B2v[t] = B * B;
        }
        #pragma unroll
        for (int j = 0; j < 4; ++j) {
            f32x4 a = acc[i][j];
            #pragma unroll
            for (int t = 0; t < 4; ++t) {
                float g   = a[t];
                float A   = fmaf(-0.02f, g, cb2p[j]);          // 1 + 2c*ab + c*b2
                float den = fmaf(-cb01[j], Bv[t], A);          // 1 + 2c*ab + c^2*a2*b2
                float AB  = A * Bv[t];
                float num = fmaf(ra2[t] * A, A, fmaf(-(g + g), AB, cb2[j] * B2v[t]));
                float s   = sqrtf(fmaxf(num, 1e-12f));
                float h   = 0.1f * s;
                float r   = __fdividef(den + h, den - h);      // (1+x)/(1-x), x=h/den<=~0.25
                float u   = fmaf(-6.93147181f, __log2f(r), g * rinv[t] * cinv[j]);
                float sim = 7.14285714f * u;
                float e   = __expf(sim);
                bool  dg  = (rrow[t] == ccol[j]);
                float ee  = dg ? 0.f : e;
                bool  pos = (!dg) && (rlab[t] == clab[j]);
                float ps  = pos ? sim : 0.f;
                float pn  = pos ? 1.f : 0.f;
                rT[t] += ee; cT[j] += ee;
                rP[t] += ps; cP[j] += ps;
                rN[t] += pn; cN[j] += pn;
            }
        }
        // reduce row states across the 16 column-lanes (l15)
        #pragma unroll
        for (int t = 0; t < 4; ++t) {
            float T = rT[t], Pp = rP[t], Nn = rN[t];
            #pragma unroll
            for (int m = 1; m < 16; m <<= 1) {
                T  += __shfl_xor(T,  m, 64);
                Pp += __shfl_xor(Pp, m, 64);
                Nn += __shfl_xor(Nn, m, 64);
            }
            if (l15 == 0) {
                int rl = i * 16 + lg * 4 + t;
                redR[wr][wc][rl][0] = T; redR[wr][wc][rl][1] = Pp; redR[wr][wc][rl][2] = Nn;
            }
        }
    }
    // reduce col states across the 4 row-lane-groups (lg): masks 16, 32
    #pragma unroll
    for (int j = 0; j < 4; ++j) {
        float T = cT[j], Pp = cP[j], Nn = cN[j];
        T += __shfl_xor(T, 16, 64); Pp += __shfl_xor(Pp, 16, 64); Nn += __shfl_xor(Nn, 16, 64);
        T += __shfl_xor(T, 32, 64); Pp += __shfl_xor(Pp, 32, 64); Nn += __shfl_xor(Nn, 32, 64);
        if (lg == 0) {
            int cl = j * 16 + l15;
            redC[wc][wr][cl][0] = T; redC[wc][wr][cl][1] = Pp; redC[wc][wr][cl][2] = Nn;
        }
    }
    __syncthreads();
    if (tid < 128) {
        int w = tid >> 6, rl = tid & 63;
        float T  = redR[w][0][rl][0] + redR[w][1][rl][0];
        float Pp = redR[w][0][rl][1] + redR[w][1][rl][1];
        float Nn = redR[w][0][rl][2] + redR[w][1][rl][2];
        part[(size_t)(trow + w * 64 + rl) * GY + by] = make_float4(T, Pp, Nn, 0.f);
    } else if (bx < by) {
        int w = (tid >> 6) - 2, cl = tid & 63;
        float T  = redC[w][0][cl][0] + redC[w][1][cl][0];
        float Pp = redC[w][0][cl][1] + redC[w][1][cl][1];
        float Nn = redC[w][0][cl][2] + redC[w][1][cl][2];
        part[(size_t)(tcol + w * 64 + cl) * GY + bx] = make_float4(T, Pp, Nn, 0.f);
    }
}

// combine 32 tile partials per row. Row max M == 7.142857 (diag), so
// log(sum exp_logits + 1e-10) folds to log(T + 1e-10*e^M) = log(T + 1.26504e-7).
__global__ void k_final(const float4* __restrict__ part, float* __restrict__ out) {
    int row = blockIdx.x * 256 + threadIdx.x;
    float T = 0.f, P = 0.f, N = 0.f;
    #pragma unroll
    for (int k = 0; k < GY; ++k) {
        float4 p = part[(size_t)row * GY + k];
        T += p.x; P += p.y; N += p.z;
    }
    float v = (N < 1e-6f) ? 0.f
            : (__logf(T + 1.265037e-7f) - P / N) * (1.0f / NTOT);
    #pragma unroll
    for (int off = 32; off > 0; off >>= 1) v += __shfl_xor(v, off, 64);
    __shared__ float wsum[4];
    int wd = threadIdx.x >> 6, lane = threadIdx.x & 63;
    if (lane == 0) wsum[wd] = v;
    __syncthreads();
    if (threadIdx.x == 0) atomicAdd(out, wsum[0] + wsum[1] + wsum[2] + wsum[3]);
}

extern "C" void kernel_launch(void* const* d_in, const int* in_sizes, int n_in,
                              void* d_out, int out_size, void* d_ws, size_t ws_size,
                              hipStream_t stream) {
    const float* f      = (const float*)d_in[0];
    const int*   labels = (const int*)d_in[1];
    float* out = (float*)d_out;

    __bf16* fb   = (__bf16*)d_ws;                                            // 2 MiB
    float*  sq   = (float*)((char*)d_ws + (size_t)NTOT * DIMK * 2);          // 16 KiB
    float4* part = (float4*)((char*)d_ws + (size_t)NTOT * DIMK * 2 + 65536); // 2 MiB

    k_prep <<<dim3(NTOT / 4), dim3(256), 0, stream>>>(f, fb, sq, out);
    k_main <<<dim3(GY, GY),   dim3(256), 0, stream>>>(fb, labels, sq, part);
    k_final<<<dim3(NTOT / 256), dim3(256), 0, stream>>>(part, out);
}

// Round 7
// 98.517 us; speedup vs baseline: 1.5895x; 1.5895x over previous
//
#include <hip/hip_runtime.h>
#include <math.h>

#define NTOT 4096
#define BSZH 2048
#define DIMK 256
#define GY   32            // 4096/128 column tiles

typedef __bf16 bf16x8 __attribute__((ext_vector_type(8)));
typedef __bf16 bf16x4 __attribute__((ext_vector_type(4)));
typedef float  f32x4  __attribute__((ext_vector_type(4)));

// fp32 -> bf16 fragment-major scatter + row squared norms + zero out.
// Fragment layout: chunk C = (p, g), p = row>>4 (256 panels), g = k>>3 (32 groups).
// Chunk holds 16 lanes x 16B: lane r = row&15 gets f[p*16+r][g*8 .. g*8+7] as bf16x8.
// k_main then loads a full A/B fragment as base + lane*16 (1KB linear per wave).
__global__ __launch_bounds__(256) void k_prep(const float* __restrict__ f,
                                              __bf16* __restrict__ fbf,
                                              float* __restrict__ sq,
                                              float* __restrict__ out) {
    if (blockIdx.x == 0 && threadIdx.x == 0) out[0] = 0.0f;
    int row  = blockIdx.x * 4 + (threadIdx.x >> 6);
    int lane = threadIdx.x & 63;
    float4 v = *(const float4*)(f + row * DIMK + lane * 4);
    bf16x4 pk;
    pk[0] = (__bf16)v.x; pk[1] = (__bf16)v.y; pk[2] = (__bf16)v.z; pk[3] = (__bf16)v.w;
    int p = row >> 4, rr = row & 15, g = lane >> 1, half = lane & 1;
    *(bf16x4*)(fbf + (size_t)(p * 32 + g) * 128 + rr * 8 + half * 4) = pk;
    float s = v.x*v.x + v.y*v.y + v.z*v.z + v.w*v.w;
    #pragma unroll
    for (int off = 32; off > 0; off >>= 1) s += __shfl_xor(s, off, 64);
    if (lane == 0) sq[row] = s;
}

// Full 128x128 tile per block (no symmetry: parallelism > redundancy).
// No LDS, no barriers in the K-loop: fragment loads are linear from fbf.
__global__ __launch_bounds__(256) void k_main(const __bf16* __restrict__ fbf,
                                              const int* __restrict__ labels,
                                              const float* __restrict__ sq,
                                              float4* __restrict__ part) {
    const int tid = threadIdx.x;
    const int wid = tid >> 6, lane = tid & 63;
    const int l15 = lane & 15, lg = lane >> 4;
    const int wr  = wid >> 1,  wc = wid & 1;
    const int bx = blockIdx.x, by = blockIdx.y;
    const int trow = bx * 128, tcol = by * 128;
    const int rowpan = bx * 8 + wr * 4;     // first 16-row panel of this wave's rows
    const int colpan = by * 8 + wc * 4;

    const char* base = (const char*)fbf + lane * 16;
    const char* ap[4]; const char* bp[4];
    #pragma unroll
    for (int i = 0; i < 4; ++i) {
        ap[i] = base + (size_t)(rowpan + i) * 8192;   // panel stride: 32 chunks * 256B
        bp[i] = base + (size_t)(colpan + i) * 8192;
    }

    f32x4 acc[4][4];
    #pragma unroll
    for (int i = 0; i < 4; ++i)
        #pragma unroll
        for (int j = 0; j < 4; ++j) acc[i][j] = (f32x4){0.f, 0.f, 0.f, 0.f};

#define LDA(A_, B_, S) { \
    _Pragma("unroll") for (int i = 0; i < 4; ++i) { \
        A_[i] = *(const bf16x8*)(ap[i] + (S) * 1024); \
        B_[i] = *(const bf16x8*)(bp[i] + (S) * 1024); } }
#define FMA(A_, B_) { \
    _Pragma("unroll") for (int i = 0; i < 4; ++i) \
    _Pragma("unroll") for (int j = 0; j < 4; ++j) \
        acc[i][j] = __builtin_amdgcn_mfma_f32_16x16x32_bf16(A_[i], B_[j], acc[i][j], 0, 0, 0); }

    bf16x8 aA[4], bA[4], aB[4], bB[4];
    LDA(aA, bA, 0);
    LDA(aB, bB, 1); FMA(aA, bA);
    LDA(aA, bA, 2); FMA(aB, bB);
    LDA(aB, bB, 3); FMA(aA, bA);
    LDA(aA, bA, 4); FMA(aB, bB);
    LDA(aB, bB, 5); FMA(aA, bA);
    LDA(aA, bA, 6); FMA(aB, bB);
    LDA(aB, bB, 7); FMA(aA, bA);
    FMA(aB, bB);
#undef LDA
#undef FMA

    // ---- epilogue (row partials only) ----
    float cb2[4], cb2p[4], cb01[4], cinv[4]; int clab[4], ccol[4];
    #pragma unroll
    for (int j = 0; j < 4; ++j) {
        int col = tcol + wc * 64 + j * 16 + l15;
        float b2 = sq[col];
        ccol[j] = col; cb2[j] = b2;
        cb2p[j] = fmaf(0.01f, b2, 1.0f);
        cb01[j] = 0.01f * b2;
        cinv[j] = __builtin_amdgcn_rsqf(fmaxf(b2, 1e-24f));
        clab[j] = labels[col & (BSZH - 1)];
    }

    __shared__ float redR[2][2][64][3];   // [wr][wc][row_local][T,P,N]

    #pragma unroll
    for (int i = 0; i < 4; ++i) {
        float rT[4], rP[4], rN[4];
        float ra2[4], rinv[4], Bv[4], B2v[4]; int rlab[4], rrow[4];
        #pragma unroll
        for (int t = 0; t < 4; ++t) {
            rT[t] = 0.f; rP[t] = 0.f; rN[t] = 0.f;
            int row = trow + wr * 64 + i * 16 + lg * 4 + t;
            float a2 = sq[row];
            rrow[t] = row; ra2[t] = a2;
            rinv[t] = __builtin_amdgcn_rsqf(fmaxf(a2, 1e-24f));
            rlab[t] = labels[row & (BSZH - 1)];
            float B = fmaf(-0.01f, a2, 1.0f);
            Bv[t] = B; B2v[t] = B * B;
        }
        #pragma unroll
        for (int j = 0; j < 4; ++j) {
            f32x4 a = acc[i][j];
            #pragma unroll
            for (int t = 0; t < 4; ++t) {
                float g   = a[t];
                float A   = fmaf(-0.02f, g, cb2p[j]);          // 1 + 2c*ab + c*b2
                float den = fmaf(-cb01[j], Bv[t], A);          // 1 + 2c*ab + c^2*a2*b2
                float AB  = A * Bv[t];
                float num = fmaf(ra2[t] * A, A, fmaf(-(g + g), AB, cb2[j] * B2v[t]));
                float s   = __builtin_amdgcn_sqrtf(fmaxf(num, 1e-12f));
                float h   = 0.1f * s;                          // x*den, x <= ~0.2 (cap never hits)
                float r   = (den + h) * __builtin_amdgcn_rcpf(den - h);
                float ang = g * rinv[t] * cinv[j];
                // sim = -49.5105*log2(r) + 7.142857*ang ; e = exp(sim) = exp2(tq)
                float tq  = fmaf(-71.4285714f, __builtin_amdgcn_logf(r), 10.3058781f * ang);
                float e   = __builtin_amdgcn_exp2f(tq);
                bool  dg  = (rrow[t] == ccol[j]);
                bool  pos = (!dg) && (rlab[t] == clab[j]);
                rT[t] += dg ? 0.f : e;
                rP[t] += pos ? 0.69314718f * tq : 0.f;         // sim
                rN[t] += pos ? 1.f : 0.f;
            }
        }
        // reduce row states across the 16 column-lanes (l15)
        #pragma unroll
        for (int t = 0; t < 4; ++t) {
            float T = rT[t], Pp = rP[t], Nn = rN[t];
            #pragma unroll
            for (int m = 1; m < 16; m <<= 1) {
                T  += __shfl_xor(T,  m, 64);
                Pp += __shfl_xor(Pp, m, 64);
                Nn += __shfl_xor(Nn, m, 64);
            }
            if (l15 == 0) {
                int rl = i * 16 + lg * 4 + t;
                redR[wr][wc][rl][0] = T; redR[wr][wc][rl][1] = Pp; redR[wr][wc][rl][2] = Nn;
            }
        }
    }
    __syncthreads();
    if (tid < 128) {
        int w = tid >> 6, rl = tid & 63;
        float T  = redR[w][0][rl][0] + redR[w][1][rl][0];
        float Pp = redR[w][0][rl][1] + redR[w][1][rl][1];
        float Nn = redR[w][0][rl][2] + redR[w][1][rl][2];
        part[(size_t)(trow + w * 64 + rl) * GY + by] = make_float4(T, Pp, Nn, 0.f);
    }
}

// combine 32 tile partials per row. Row max M == diag == 7.142857 exactly,
// so log(sum exp_logits + 1e-10) = -M + log(T + 1e-10*e^M), M cancels in
// log_prob; 1e-10*e^M = 1.265037e-7.
__global__ void k_final(const float4* __restrict__ part, float* __restrict__ out) {
    int row = blockIdx.x * 256 + threadIdx.x;
    float T = 0.f, P = 0.f, N = 0.f;
    #pragma unroll
    for (int k = 0; k < GY; ++k) {
        float4 p = part[(size_t)row * GY + k];
        T += p.x; P += p.y; N += p.z;
    }
    float v = (N < 1e-6f) ? 0.f
            : (__logf(T + 1.265037e-7f) - P / N) * (1.0f / NTOT);
    #pragma unroll
    for (int off = 32; off > 0; off >>= 1) v += __shfl_xor(v, off, 64);
    __shared__ float wsum[4];
    int wd = threadIdx.x >> 6, lane = threadIdx.x & 63;
    if (lane == 0) wsum[wd] = v;
    __syncthreads();
    if (threadIdx.x == 0) atomicAdd(out, wsum[0] + wsum[1] + wsum[2] + wsum[3]);
}

extern "C" void kernel_launch(void* const* d_in, const int* in_sizes, int n_in,
                              void* d_out, int out_size, void* d_ws, size_t ws_size,
                              hipStream_t stream) {
    const float* f      = (const float*)d_in[0];
    const int*   labels = (const int*)d_in[1];
    float* out = (float*)d_out;

    __bf16* fbf  = (__bf16*)d_ws;                                            // 2 MiB
    float*  sq   = (float*)((char*)d_ws + (size_t)NTOT * DIMK * 2);          // 16 KiB
    float4* part = (float4*)((char*)d_ws + (size_t)NTOT * DIMK * 2 + 65536); // 2 MiB

    k_prep <<<dim3(NTOT / 4), dim3(256), 0, stream>>>(f, fbf, sq, out);
    k_main <<<dim3(GY, GY),   dim3(256), 0, stream>>>(fbf, labels, sq, part);
    k_final<<<dim3(NTOT / 256), dim3(256), 0, stream>>>(part, out);
}

// Round 8
// 94.117 us; speedup vs baseline: 1.6638x; 1.0468x over previous
//
#include <hip/hip_runtime.h>
#include <math.h>

#define NTOT 4096
#define BSZH 2048
#define DIMK 256
#define GY   32            // 4096/128 tiles per dimension

typedef __bf16 bf16x8 __attribute__((ext_vector_type(8)));
typedef float  f32x4  __attribute__((ext_vector_type(4)));

// fp32 -> bf16 fragment-major layout + row squared norms + zero out.
// Fragment layout: panel p = row>>4 (256 panels of 16 rows); within a panel,
// chunk g = k>>3 (32 chunks); chunk = 16 lanes x 16B: lane r gets
// f[p*16+r][g*8..g*8+7] as bf16x8. k_main loads a fragment as base+lane*16.
// One block per panel; LDS transpose so global loads AND stores are coalesced.
__global__ __launch_bounds__(256) void k_prep(const float* __restrict__ f,
                                              __bf16* __restrict__ fbf,
                                              float* __restrict__ sq,
                                              float* __restrict__ out) {
    if (blockIdx.x == 0 && threadIdx.x == 0) out[0] = 0.0f;
    const int tid   = threadIdx.x;
    const int panel = blockIdx.x;
    const int r  = tid >> 4;     // 0..15 row within panel
    const int gg = tid & 15;     // 0..15 k-group
    __shared__ __align__(16) __bf16 lp[4096];   // 8 KiB staging (panel, fragment-major)

    float s = 0.f;
    #pragma unroll
    for (int h = 0; h < 2; ++h) {
        int g = gg + h * 16;
        const float* src = f + (size_t)(panel * 16 + r) * DIMK + g * 8;
        float4 v0 = *(const float4*)(src);
        float4 v1 = *(const float4*)(src + 4);
        s += v0.x*v0.x + v0.y*v0.y + v0.z*v0.z + v0.w*v0.w
           + v1.x*v1.x + v1.y*v1.y + v1.z*v1.z + v1.w*v1.w;
        bf16x8 pk;
        pk[0] = (__bf16)v0.x; pk[1] = (__bf16)v0.y; pk[2] = (__bf16)v0.z; pk[3] = (__bf16)v0.w;
        pk[4] = (__bf16)v1.x; pk[5] = (__bf16)v1.y; pk[6] = (__bf16)v1.z; pk[7] = (__bf16)v1.w;
        *(bf16x8*)(lp + g * 128 + r * 8) = pk;   // byte off g*256 + r*16
    }
    #pragma unroll
    for (int m = 1; m < 16; m <<= 1) s += __shfl_xor(s, m, 64);
    if (gg == 0) sq[panel * 16 + r] = s;
    __syncthreads();
    const bf16x8* srcv = (const bf16x8*)lp;
    bf16x8* dst = (bf16x8*)(fbf + (size_t)panel * 4096);
    dst[tid]       = srcv[tid];
    dst[tid + 256] = srcv[tid + 256];
}

// Full 128x128 tile per block; fragment loads linear from fbf (L2-resident).
// launch_bounds(256,4): cap VGPR at 128 so 4 blocks/CU -> grid runs in ONE round.
__global__ __launch_bounds__(256, 4) void k_main(const __bf16* __restrict__ fbf,
                                                 const int* __restrict__ labels,
                                                 const float* __restrict__ sq,
                                                 float4* __restrict__ part) {
    const int tid = threadIdx.x;
    const int wid = tid >> 6, lane = tid & 63;
    const int l15 = lane & 15, lg = lane >> 4;
    const int wr  = wid >> 1,  wc = wid & 1;
    const int bx = blockIdx.x, by = blockIdx.y;
    const int trow = bx * 128, tcol = by * 128;
    const int rowpan = bx * 8 + wr * 4;
    const int colpan = by * 8 + wc * 4;
    const bool tilediag = (bx == by) && (wr == wc);

    const char* base = (const char*)fbf + lane * 16;

    f32x4 acc[4][4];
    #pragma unroll
    for (int i = 0; i < 4; ++i)
        #pragma unroll
        for (int j = 0; j < 4; ++j) acc[i][j] = (f32x4){0.f, 0.f, 0.f, 0.f};

    #pragma unroll
    for (int s = 0; s < 8; ++s) {
        bf16x8 av[4], bv[4];
        #pragma unroll
        for (int i = 0; i < 4; ++i) {
            av[i] = *(const bf16x8*)(base + (size_t)(rowpan + i) * 8192 + s * 1024);
            bv[i] = *(const bf16x8*)(base + (size_t)(colpan + i) * 8192 + s * 1024);
        }
        #pragma unroll
        for (int i = 0; i < 4; ++i)
            #pragma unroll
            for (int j = 0; j < 4; ++j)
                acc[i][j] = __builtin_amdgcn_mfma_f32_16x16x32_bf16(av[i], bv[j], acc[i][j], 0, 0, 0);
    }

    // ---- epilogue (row partials only) ----
    float cb2[4], cb2p[4], cb01[4], cinv[4]; int clab[4];
    #pragma unroll
    for (int j = 0; j < 4; ++j) {
        int col = tcol + wc * 64 + j * 16 + l15;
        float b2 = sq[col];
        cb2[j]  = b2;
        cb2p[j] = fmaf(0.01f, b2, 1.0f);
        cb01[j] = 0.01f * b2;
        cinv[j] = __builtin_amdgcn_rsqf(fmaxf(b2, 1e-24f));
        clab[j] = labels[col & (BSZH - 1)];
    }

    __shared__ float redR[2][2][64][3];   // [wr][wc][row_local][T,P,N]

    #pragma unroll
    for (int i = 0; i < 4; ++i) {
        float rT[4], rP[4], rN[4];
        float ra2[4], rinv[4], Bv[4], B2v[4]; int rlab[4];
        #pragma unroll
        for (int t = 0; t < 4; ++t) {
            rT[t] = 0.f; rP[t] = 0.f; rN[t] = 0.f;
            int row = trow + wr * 64 + i * 16 + lg * 4 + t;
            float a2 = sq[row];
            ra2[t]  = a2;
            rinv[t] = __builtin_amdgcn_rsqf(fmaxf(a2, 1e-24f));
            rlab[t] = labels[row & (BSZH - 1)];
            float B = fmaf(-0.01f, a2, 1.0f);
            Bv[t] = B; B2v[t] = B * B;
        }
        #pragma unroll
        for (int j = 0; j < 4; ++j) {
            f32x4 a = acc[i][j];
            #pragma unroll
            for (int t = 0; t < 4; ++t) {
                float g   = a[t];
                float A   = fmaf(-0.02f, g, cb2p[j]);          // 1 + 2c*ab + c*b2
                float den = fmaf(-cb01[j], Bv[t], A);          // 1 + 2c*ab + c^2*a2*b2
                float AB  = A * Bv[t];
                float num = fmaf(ra2[t] * A, A, fmaf(-(g + g), AB, cb2[j] * B2v[t]));
                float sdt = __builtin_amdgcn_sqrtf(fmaxf(num, 1e-12f));
                float h   = 0.1f * sdt;                        // x*den, x <= ~0.25
                float r   = (den + h) * __builtin_amdgcn_rcpf(den - h);
                float ang = g * rinv[t] * cinv[j];
                // sim = -49.5105*log2(r) + 7.142857*ang ; e^sim = exp2(tq)
                float tq  = fmaf(-71.4285714f, __builtin_amdgcn_logf(r), 10.3058781f * ang);
                float e   = __builtin_amdgcn_exp2f(tq);
                bool  dg  = tilediag && (i == j) && (l15 == lg * 4 + t);
                bool  pos = (!dg) && (rlab[t] == clab[j]);
                rT[t] += dg ? 0.f : e;
                rP[t] += pos ? 0.69314718f * tq : 0.f;         // sim
                rN[t] += pos ? 1.f : 0.f;
            }
        }
        #pragma unroll
        for (int t = 0; t < 4; ++t) {
            float T = rT[t], Pp = rP[t], Nn = rN[t];
            #pragma unroll
            for (int m = 1; m < 16; m <<= 1) {
                T  += __shfl_xor(T,  m, 64);
                Pp += __shfl_xor(Pp, m, 64);
                Nn += __shfl_xor(Nn, m, 64);
            }
            if (l15 == 0) {
                int rl = i * 16 + lg * 4 + t;
                redR[wr][wc][rl][0] = T; redR[wr][wc][rl][1] = Pp; redR[wr][wc][rl][2] = Nn;
            }
        }
    }
    __syncthreads();
    if (tid < 128) {
        int w = tid >> 6, rl = tid & 63;
        float T  = redR[w][0][rl][0] + redR[w][1][rl][0];
        float Pp = redR[w][0][rl][1] + redR[w][1][rl][1];
        float Nn = redR[w][0][rl][2] + redR[w][1][rl][2];
        // part layout [by][row]: lane-coalesced write here, coalesced read in k_final
        part[(size_t)by * NTOT + trow + w * 64 + rl] = make_float4(T, Pp, Nn, 0.f);
    }
}

// combine 32 tile partials per row. Row max M == diag == 7.142857 exactly
// (dsim<=0, ang<=1, equality only on the diagonal), so the stop_gradient
// shift cancels and log(sum exp_logits + 1e-10) folds to
// log(T + 1e-10*e^M) with 1e-10*e^M = 1.265037e-7.
__global__ void k_final(const float4* __restrict__ part, float* __restrict__ out) {
    int row = blockIdx.x * 256 + threadIdx.x;
    float T = 0.f, P = 0.f, N = 0.f;
    #pragma unroll
    for (int k = 0; k < GY; ++k) {
        float4 p = part[(size_t)k * NTOT + row];
        T += p.x; P += p.y; N += p.z;
    }
    float v = (N < 1e-6f) ? 0.f
            : (__logf(T + 1.265037e-7f) - P / N) * (1.0f / NTOT);
    #pragma unroll
    for (int off = 32; off > 0; off >>= 1) v += __shfl_xor(v, off, 64);
    __shared__ float wsum[4];
    int wd = threadIdx.x >> 6, lane = threadIdx.x & 63;
    if (lane == 0) wsum[wd] = v;
    __syncthreads();
    if (threadIdx.x == 0) atomicAdd(out, wsum[0] + wsum[1] + wsum[2] + wsum[3]);
}

extern "C" void kernel_launch(void* const* d_in, const int* in_sizes, int n_in,
                              void* d_out, int out_size, void* d_ws, size_t ws_size,
                              hipStream_t stream) {
    const float* f      = (const float*)d_in[0];
    const int*   labels = (const int*)d_in[1];
    float* out = (float*)d_out;

    __bf16* fbf  = (__bf16*)d_ws;                                            // 2 MiB
    float*  sq   = (float*)((char*)d_ws + (size_t)NTOT * DIMK * 2);          // 16 KiB
    float4* part = (float4*)((char*)d_ws + (size_t)NTOT * DIMK * 2 + 65536); // 2 MiB

    k_prep <<<dim3(NTOT / 16), dim3(256), 0, stream>>>(f, fbf, sq, out);
    k_main <<<dim3(GY, GY),    dim3(256), 0, stream>>>(fbf, labels, sq, part);
    k_final<<<dim3(NTOT / 256), dim3(256), 0, stream>>>(part, out);
}

// Round 10
// 92.398 us; speedup vs baseline: 1.6948x; 1.0186x over previous
//
#include <hip/hip_runtime.h>
#include <math.h>

#define NTOT 4096
#define BSZH 2048
#define DIMK 256
#define GY   32            // 4096/128 tiles per dimension

typedef __bf16 bf16x8 __attribute__((ext_vector_type(8)));
typedef float  f32x4  __attribute__((ext_vector_type(4)));

// fp32 -> bf16 fragment-major layout + row squared norms + zero out.
// Fragment layout: panel p = row>>4 (256 panels of 16 rows); within a panel,
// chunk g = k>>3 (32 chunks); chunk = 16 lanes x 16B: lane r gets
// f[p*16+r][g*8..g*8+7] as bf16x8. k_main loads a fragment as base+lane*16.
__global__ __launch_bounds__(256) void k_prep(const float* __restrict__ f,
                                              __bf16* __restrict__ fbf,
                                              float* __restrict__ sq,
                                              float* __restrict__ out) {
    if (blockIdx.x == 0 && threadIdx.x == 0) out[0] = 0.0f;
    const int tid   = threadIdx.x;
    const int panel = blockIdx.x;
    const int r  = tid >> 4;     // 0..15 row within panel
    const int gg = tid & 15;     // 0..15 k-group
    __shared__ __align__(16) __bf16 lp[4096];   // 8 KiB staging

    float s = 0.f;
    #pragma unroll
    for (int h = 0; h < 2; ++h) {
        int g = gg + h * 16;
        const float* src = f + (size_t)(panel * 16 + r) * DIMK + g * 8;
        float4 v0 = *(const float4*)(src);
        float4 v1 = *(const float4*)(src + 4);
        s += v0.x*v0.x + v0.y*v0.y + v0.z*v0.z + v0.w*v0.w
           + v1.x*v1.x + v1.y*v1.y + v1.z*v1.z + v1.w*v1.w;
        bf16x8 pk;
        pk[0] = (__bf16)v0.x; pk[1] = (__bf16)v0.y; pk[2] = (__bf16)v0.z; pk[3] = (__bf16)v0.w;
        pk[4] = (__bf16)v1.x; pk[5] = (__bf16)v1.y; pk[6] = (__bf16)v1.z; pk[7] = (__bf16)v1.w;
        *(bf16x8*)(lp + g * 128 + r * 8) = pk;
    }
    #pragma unroll
    for (int m = 1; m < 16; m <<= 1) s += __shfl_xor(s, m, 64);
    if (gg == 0) sq[panel * 16 + r] = s;
    __syncthreads();
    const bf16x8* srcv = (const bf16x8*)lp;
    bf16x8* dst = (bf16x8*)(fbf + (size_t)panel * 4096);
    dst[tid]       = srcv[tid];
    dst[tid + 256] = srcv[tid + 256];
}

// Full 128x128 tile per block; fragment loads linear from fbf (L2-resident).
// Register-lean K-loop: av[4] held, bv streamed per-j so the natural live set
// fits the 128-VGPR / 4-blocks-per-CU budget without spilling.
__global__ __launch_bounds__(256, 4) void k_main(const __bf16* __restrict__ fbf,
                                                 const int* __restrict__ labels,
                                                 const float* __restrict__ sq,
                                                 float4* __restrict__ part) {
    const int tid = threadIdx.x;
    const int wid = tid >> 6, lane = tid & 63;
    const int l15 = lane & 15, lg = lane >> 4;
    const int wr  = wid >> 1,  wc = wid & 1;
    const int bx = blockIdx.x, by = blockIdx.y;
    const int trow = bx * 128, tcol = by * 128;
    const bool tilediag = (bx == by) && (wr == wc);

    const char* base = (const char*)fbf + lane * 16;
    const char* arow = base + (size_t)(bx * 8 + wr * 4) * 8192;
    const char* brow = base + (size_t)(by * 8 + wc * 4) * 8192;

    f32x4 acc[4][4];
    #pragma unroll
    for (int i = 0; i < 4; ++i)
        #pragma unroll
        for (int j = 0; j < 4; ++j) acc[i][j] = (f32x4){0.f, 0.f, 0.f, 0.f};

    #pragma unroll
    for (int s = 0; s < 8; ++s) {
        bf16x8 av[4];
        #pragma unroll
        for (int i = 0; i < 4; ++i)
            av[i] = *(const bf16x8*)(arow + (size_t)i * 8192 + s * 1024);
        #pragma unroll
        for (int j = 0; j < 4; ++j) {
            bf16x8 bv = *(const bf16x8*)(brow + (size_t)j * 8192 + s * 1024);
            #pragma unroll
            for (int i = 0; i < 4; ++i)
                acc[i][j] = __builtin_amdgcn_mfma_f32_16x16x32_bf16(av[i], bv, acc[i][j], 0, 0, 0);
        }
    }

    // ---- epilogue (row partials only) ----
    float cb2[4], cb2p[4], cb01[4], cinv[4]; int clab[4];
    #pragma unroll
    for (int j = 0; j < 4; ++j) {
        int col = tcol + wc * 64 + j * 16 + l15;
        float b2 = sq[col];
        cb2[j]  = b2;
        cb2p[j] = fmaf(0.01f, b2, 1.0f);
        cb01[j] = 0.01f * b2;
        cinv[j] = __builtin_amdgcn_rsqf(fmaxf(b2, 1e-24f));
        clab[j] = labels[col & (BSZH - 1)];
    }

    __shared__ float redR[2][2][64][3];   // [wr][wc][row_local][T,P,N]

    #pragma unroll
    for (int i = 0; i < 4; ++i) {
        float rT[4], rP[4], rN[4];
        float ra2[4], rinv[4], Bv[4], B2v[4]; int rlab[4];
        #pragma unroll
        for (int t = 0; t < 4; ++t) {
            rT[t] = 0.f; rP[t] = 0.f; rN[t] = 0.f;
            int row = trow + wr * 64 + i * 16 + lg * 4 + t;
            float a2 = sq[row];
            ra2[t]  = a2;
            rinv[t] = __builtin_amdgcn_rsqf(fmaxf(a2, 1e-24f));
            rlab[t] = labels[row & (BSZH - 1)];
            float B = fmaf(-0.01f, a2, 1.0f);
            Bv[t] = B; B2v[t] = B * B;
        }
        #pragma unroll
        for (int j = 0; j < 4; ++j) {
            f32x4 a = acc[i][j];
            #pragma unroll
            for (int t = 0; t < 4; ++t) {
                float g   = a[t];
                float A   = fmaf(-0.02f, g, cb2p[j]);          // 1 + 2c*ab + c*b2
                float den = fmaf(-cb01[j], Bv[t], A);          // 1 + 2c*ab + c^2*a2*b2
                float AB  = A * Bv[t];
                float num = fmaf(ra2[t] * A, A, fmaf(-(g + g), AB, cb2[j] * B2v[t]));
                float sdt = __builtin_amdgcn_sqrtf(fmaxf(num, 1e-12f));
                float h   = 0.1f * sdt;                        // x*den, x <= ~0.25
                float r   = (den + h) * __builtin_amdgcn_rcpf(den - h);
                float ang = g * rinv[t] * cinv[j];
                // sim = -49.5105*log2(r) + 7.142857*ang ; e^sim = exp2(tq)
                float tq  = fmaf(-71.4285714f, __builtin_amdgcn_logf(r), 10.3058781f * ang);
                float e   = __builtin_amdgcn_exp2f(tq);
                bool  dg  = tilediag && (i == j) && (l15 == lg * 4 + t);
                bool  pos = (!dg) && (rlab[t] == clab[j]);
                rT[t] += dg ? 0.f : e;
                rP[t] += pos ? 0.69314718f * tq : 0.f;         // sim
                rN[t] += pos ? 1.f : 0.f;
            }
        }
        #pragma unroll
        for (int t = 0; t < 4; ++t) {
            float T = rT[t], Pp = rP[t], Nn = rN[t];
            #pragma unroll
            for (int m = 1; m < 16; m <<= 1) {
                T  += __shfl_xor(T,  m, 64);
                Pp += __shfl_xor(Pp, m, 64);
                Nn += __shfl_xor(Nn, m, 64);
            }
            if (l15 == 0) {
                int rl = i * 16 + lg * 4 + t;
                redR[wr][wc][rl][0] = T; redR[wr][wc][rl][1] = Pp; redR[wr][wc][rl][2] = Nn;
            }
        }
    }
    __syncthreads();
    if (tid < 128) {
        int w = tid >> 6, rl = tid & 63;
        float T  = redR[w][0][rl][0] + redR[w][1][rl][0];
        float Pp = redR[w][0][rl][1] + redR[w][1][rl][1];
        float Nn = redR[w][0][rl][2] + redR[w][1][rl][2];
        part[(size_t)by * NTOT + trow + w * 64 + rl] = make_float4(T, Pp, Nn, 0.f);
    }
}

// combine 32 tile partials per row. Row max M == diag == 7.142857 exactly
// (dsim<=0, ang<=1, equality only on the diagonal), so the stop_gradient
// shift cancels and log(sum exp_logits + 1e-10) folds to
// log(T + 1e-10*e^M) with 1e-10*e^M = 1.265037e-7.
__global__ void k_final(const float4* __restrict__ part, float* __restrict__ out) {
    int row = blockIdx.x * 256 + threadIdx.x;
    float T = 0.f, P = 0.f, N = 0.f;
    #pragma unroll
    for (int k = 0; k < GY; ++k) {
        float4 p = part[(size_t)k * NTOT + row];
        T += p.x; P += p.y; N += p.z;
    }
    float v = (N < 1e-6f) ? 0.f
            : (__logf(T + 1.265037e-7f) - P / N) * (1.0f / NTOT);
    #pragma unroll
    for (int off = 32; off > 0; off >>= 1) v += __shfl_xor(v, off, 64);
    __shared__ float wsum[4];
    int wd = threadIdx.x >> 6, lane = threadIdx.x & 63;
    if (lane == 0) wsum[wd] = v;
    __syncthreads();
    if (threadIdx.x == 0) atomicAdd(out, wsum[0] + wsum[1] + wsum[2] + wsum[3]);
}

extern "C" void kernel_launch(void* const* d_in, const int* in_sizes, int n_in,
                              void* d_out, int out_size, void* d_ws, size_t ws_size,
                              hipStream_t stream) {
    const float* f      = (const float*)d_in[0];
    const int*   labels = (const int*)d_in[1];
    float* out = (float*)d_out;

    __bf16* fbf  = (__bf16*)d_ws;                                            // 2 MiB
    float*  sq   = (float*)((char*)d_ws + (size_t)NTOT * DIMK * 2);          // 16 KiB
    float4* part = (float4*)((char*)d_ws + (size_t)NTOT * DIMK * 2 + 65536); // 2 MiB

    k_prep <<<dim3(NTOT / 16), dim3(256), 0, stream>>>(f, fbf, sq, out);
    k_main <<<dim3(GY, GY),    dim3(256), 0, stream>>>(fbf, labels, sq, part);
    k_final<<<dim3(NTOT / 256), dim3(256), 0, stream>>>(part, out);
}